// Round 3
// baseline (219.354 us; speedup 1.0000x reference)
//
#include <hip/hip_runtime.h>
#include <hip/hip_bf16.h>
#include <math.h>

#pragma clang fp contract(off)

#define BSZ   16
#define NMAXG 64
#define NAA   8400
#define NCC   80
#define KTOP  13
#define CAP   768
#define MCMAX 6656
#define CLMAX 13312

// CIoU (clipped at 0) with precomputed ga = w1*h1, pa = w2*h2, da = atan(w2/h2)-atan(w1/h1)
__device__ __forceinline__ float ciou_pre(float gx1, float gy1, float gx2, float gy2,
                                          float px1, float py1, float px2, float py2,
                                          float ga, float pa, float da) {
    const float E = 1e-7f;
    float iw = fminf(gx2, px2) - fmaxf(gx1, px1); iw = fmaxf(iw, 0.0f);
    float ih = fminf(gy2, py2) - fmaxf(gy1, py1); ih = fmaxf(ih, 0.0f);
    float inter = iw * ih;
    float uni = ga + pa - inter + E;
    float iou = inter / uni;
    float cw = fmaxf(gx2, px2) - fminf(gx1, px1);
    float ch = fmaxf(gy2, py2) - fminf(gy1, py1);
    float c2 = cw * cw + ch * ch + E;
    float dx = px1 + px2 - gx1 - gx2;
    float dy = py1 + py2 - gy1 - gy2;
    float rho2 = (dx * dx + dy * dy) / 4.0f;
    float v = 0.4052847345693511f * (da * da);   // 4/pi^2
    float alpha = v / (v - iou + (1.0f + E));
    float r = iou - (rho2 / c2 + v * alpha);
    return fmaxf(r, 0.0f);
}

// ---- K0: per-anchor precompute {pd_r, area, r2, atan(r2)}; per-row {gt_r, area, r1, atan(r1)} ----
__global__ __launch_bounds__(256) void k_pre(
    const float* __restrict__ pd_bboxes, const float* __restrict__ gt_bboxes,
    float4* __restrict__ precomp, float4* __restrict__ rowpre)
{
    int i = blockIdx.x * 256 + threadIdx.x;
    if (i < BSZ * NAA) {
        float4 p = ((const float4*)pd_bboxes)[i];
        float w2 = p.z - p.x, h2 = p.w - p.y + 1e-7f;
        float r2 = w2 / h2;
        float4 q;
        q.x = fminf(w2, h2) / fmaxf(w2, h2);   // pd_r
        q.y = w2 * h2;                         // pa
        q.z = r2;                              // r2
        q.w = atanf(r2);                       // at2
        precomp[i] = q;
    }
    if (i < BSZ * NMAXG) {
        float4 g = ((const float4*)gt_bboxes)[i];
        float w1 = g.z - g.x, h1 = g.w - g.y + 1e-7f;
        float r1 = w1 / h1;
        float4 q;
        q.x = fminf(w1, h1) / fmaxf(w1, h1);   // gt_r
        q.y = w1 * h1;                         // ga
        q.z = r1;                              // r1
        q.w = atanf(r1);                       // at1
        rowpre[i] = q;
    }
}

// ---- K1: one block per (b,n): cost maxes + compaction, metric, single-wave register top-13 ----
__global__ __launch_bounds__(256) void k_rows(
    const float* __restrict__ pd_scores, const float* __restrict__ pd_bboxes,
    const float* __restrict__ anc, const int* __restrict__ gt_labels,
    const float* __restrict__ gt_bboxes, const float* __restrict__ mask_gt,
    const float4* __restrict__ precomp, const float4* __restrict__ rowpre,
    unsigned int* __restrict__ fg, float* __restrict__ rowmax,
    int* __restrict__ finaln, float* __restrict__ fnalign, float* __restrict__ fnov,
    int* __restrict__ mc_count, int* __restrict__ mlist,
    int* __restrict__ cl_count, int* __restrict__ clist)
{
    __shared__ int cidx[CAP];
    __shared__ unsigned long long keys[CAP];
    __shared__ float ovs[CAP];
    __shared__ float red[3][4];
    __shared__ int s_cnt, s_pos;

    int row = blockIdx.x;            // b*NMAXG + n
    int b = row >> 6, n = row & 63;
    int t = threadIdx.x;
    int wave = t >> 6, lane = t & 63;
    if (t == 0) { s_cnt = 0; s_pos = 0; }
    __syncthreads();

    float4 g  = ((const float4*)gt_bboxes)[row];
    float4 rp = rowpre[row];                      // gt_r, ga, r1, at1
    const float4* pc = precomp + (size_t)b * NAA;
    const float2* ap2 = (const float2*)anc;

    // phase A: full-row maxes of the 3 cost components + compact in-gt anchor list
    float ms = -1e30f, ma = -1e30f, mw = -1e30f;
    for (int a = t; a < NAA; a += 256) {
        float4 q = pc[a];                         // pd_r, pa, r2, at2
        float cs = 1.0f - fabsf(rp.x - q.x) / fmaxf(rp.x, q.x);
        float ca = 1.0f - fabsf(rp.y - q.y) / fmaxf(rp.y, q.y);
        float cw = fminf(rp.z, q.z) / fmaxf(rp.z, q.z);
        ms = fmaxf(ms, cs); ma = fmaxf(ma, ca); mw = fmaxf(mw, cw);
        float2 apv = ap2[a];
        float d = fminf(fminf(apv.x - g.x, apv.y - g.y), fminf(g.z - apv.x, g.w - apv.y));
        if (d > 1e-9f) {
            int p = atomicAdd(&s_cnt, 1);
            if (p < CAP) cidx[p] = a;
        }
    }
    for (int o = 32; o; o >>= 1) {
        ms = fmaxf(ms, __shfl_xor(ms, o));
        ma = fmaxf(ma, __shfl_xor(ma, o));
        mw = fmaxf(mw, __shfl_xor(mw, o));
    }
    if (lane == 0) { red[0][wave] = ms; red[1][wave] = ma; red[2][wave] = mw; }
    __syncthreads();
    ms = fmaxf(fmaxf(red[0][0], red[0][1]), fmaxf(red[0][2], red[0][3]));
    ma = fmaxf(fmaxf(red[1][0], red[1][1]), fmaxf(red[1][2], red[1][3]));
    mw = fmaxf(fmaxf(red[2][0], red[2][1]), fmaxf(red[2][2], red[2][3]));
    if (t == 0) { rowmax[row * 3 + 0] = ms; rowmax[row * 3 + 1] = ma; rowmax[row * 3 + 2] = mw; }
    float dms = ms + 1e-7f, dma = ma + 1e-7f, dmw = mw + 1e-7f;
    int cnt = s_cnt; cnt = cnt < CAP ? cnt : CAP;

    if (mask_gt[row] <= 0.0f) return;   // block-uniform: masked row selects nothing

    // phase B: full align metric at compact anchors only
    int lbl = gt_labels[row];
    const float* sc = pd_scores + (size_t)b * NAA * NCC + lbl;
    const float4* pb = (const float4*)pd_bboxes + (size_t)b * NAA;
    for (int j = t; j < cnt; j += 256) {
        int a = cidx[j];
        float4 p = pb[a];
        float4 q = pc[a];
        float cs = 1.0f - fabsf(rp.x - q.x) / fmaxf(rp.x, q.x);
        float ca = 1.0f - fabsf(rp.y - q.y) / fmaxf(rp.y, q.y);
        float cw = fminf(rp.z, q.z) / fmaxf(rp.z, q.z);
        float cost = ((cs / dms + cw / dmw) + ca / dma) / 3.0f;
        cost = fmaxf(cost, 0.0f);
        float ov = ciou_pre(g.x, g.y, g.z, g.w, p.x, p.y, p.z, p.w,
                            rp.y, q.y, q.w - rp.w);
        float s = sc[(size_t)a * NCC];
        float o2 = ov * ov; float o3 = o2 * ov; float ov6 = o3 * o3;
        float align = (s * ov6) * cost;
        keys[j] = ((unsigned long long)__float_as_uint(align) << 32)
                | (unsigned long long)(0xFFFFFFFFu - (unsigned)a);
        ovs[j] = ov;
        unsigned long long bal = __ballot(align > 0.0f);
        if (lane == 0 && bal) atomicAdd(&s_pos, __popcll(bal));
    }
    __syncthreads();
    if (wave != 0) return;              // no barriers below: wave 0 finishes alone

    int mpos = s_pos;
    int bA = b * NAA;

    if (mpos >= KTOP) {
        // register-resident keys: lane holds j = lane + 64*r
        unsigned long long rk[CAP / 64];
        float rov[CAP / 64];
        #pragma unroll
        for (int r = 0; r < CAP / 64; r++) {
            int j = lane + (r << 6);
            bool in = j < cnt;
            rk[r] = in ? keys[j] : 0ull;
            rov[r] = in ? ovs[j] : 0.0f;
        }
        for (int k = 0; k < KTOP; k++) {
            unsigned long long best = 0ull;
            #pragma unroll
            for (int r = 0; r < CAP / 64; r++) best = rk[r] > best ? rk[r] : best;
            for (int o = 32; o; o >>= 1) {
                unsigned long long ot = __shfl_xor(best, o);
                best = ot > best ? ot : best;
            }
            bool fnd = false; float fov = 0.0f;
            #pragma unroll
            for (int r = 0; r < CAP / 64; r++)
                if (rk[r] == best) { rk[r] = 0ull; fov = rov[r]; fnd = true; }
            if (fnd) {                   // exactly one lane (keys unique, never 0)
                int a = (int)(0xFFFFFFFFu - (unsigned)(best & 0xFFFFFFFFull));
                float al = __uint_as_float((unsigned)(best >> 32));
                int gi = bA + a;
                unsigned old = atomicAdd(&fg[gi], 1u);
                if (old == 0u) {
                    finaln[gi] = n; fnalign[gi] = al; fnov[gi] = fov;
                    int p = atomicAdd(cl_count, 1); clist[p] = gi;
                } else if (old == 1u) {
                    int p = atomicAdd(mc_count, 1); mlist[p] = gi;
                }
            }
        }
    } else {
        // <13 positives: all positives selected; remaining Z slots go to lowest-index
        // zero-valued anchors of the whole row (only in-gt ones survive the later mask).
        int Z = KTOP - mpos;
        for (int j = lane; j < cnt; j += 64) {
            unsigned long long kk = keys[j];
            int a = (int)(0xFFFFFFFFu - (unsigned)(kk & 0xFFFFFFFFull));
            bool sel;
            if ((kk >> 32) != 0ull) {
                sel = true;
            } else {
                int pcb = 0;
                for (int j2 = 0; j2 < cnt; j2++) {
                    unsigned long long k2 = keys[j2];
                    if ((k2 >> 32) != 0ull) {
                        int a2 = (int)(0xFFFFFFFFu - (unsigned)(k2 & 0xFFFFFFFFull));
                        if (a2 < a) pcb++;
                    }
                }
                sel = (a - pcb) < Z;
            }
            if (sel) {
                int gi = bA + a;
                float al = __uint_as_float((unsigned)(kk >> 32));
                unsigned old = atomicAdd(&fg[gi], 1u);
                if (old == 0u) {
                    finaln[gi] = n; fnalign[gi] = al; fnov[gi] = ovs[j];
                    int p = atomicAdd(cl_count, 1); clist[p] = gi;
                } else if (old == 1u) {
                    int p = atomicAdd(mc_count, 1); mlist[p] = gi;
                }
            }
        }
    }
}

// ---- K2: one wave per multi-claimed anchor; 64 gts across 64 lanes ----
__global__ __launch_bounds__(256) void k_multi(
    const float* __restrict__ pd_scores, const float* __restrict__ pd_bboxes,
    const int* __restrict__ gt_labels, const float* __restrict__ gt_bboxes,
    const float4* __restrict__ precomp, const float4* __restrict__ rowpre,
    const float* __restrict__ rowmax, const int* __restrict__ mc_count,
    const int* __restrict__ mlist,
    int* __restrict__ finaln, float* __restrict__ fnalign, float* __restrict__ fnov)
{
    int wave = threadIdx.x >> 6, lane = threadIdx.x & 63;
    int nwaves = gridDim.x << 2;
    int count = *mc_count;
    for (int w = (blockIdx.x << 2) + wave; w < count; w += nwaves) {
        int gi = mlist[w];                          // b*NAA + a
        int b = gi / NAA;
        int rowb = (b << 6) + lane;                 // lane = gt index n
        const float4 p  = ((const float4*)pd_bboxes)[gi];
        const float4 q  = precomp[gi];              // pd_r, pa, r2, at2
        const float4 g  = ((const float4*)gt_bboxes)[rowb];
        const float4 rp = rowpre[rowb];             // gt_r, ga, r1, at1
        float ov = ciou_pre(g.x, g.y, g.z, g.w, p.x, p.y, p.z, p.w,
                            rp.y, q.y, q.w - rp.w);
        // argmax over n, first max wins: value desc, index asc
        unsigned long long key = ((unsigned long long)__float_as_uint(ov) << 32)
                               | (unsigned long long)(63 - lane);
        unsigned long long best = key;
        for (int o = 32; o; o >>= 1) {
            unsigned long long ot = __shfl_xor(best, o);
            best = ot > best ? ot : best;
        }
        int nstar = 63 - (int)(best & 63ull);
        if (lane == nstar) {
            float cs = 1.0f - fabsf(rp.x - q.x) / fmaxf(rp.x, q.x);
            float ca = 1.0f - fabsf(rp.y - q.y) / fmaxf(rp.y, q.y);
            float cw = fminf(rp.z, q.z) / fmaxf(rp.z, q.z);
            const float* rm = rowmax + rowb * 3;
            float cost = ((cs / (rm[0] + 1e-7f) + cw / (rm[2] + 1e-7f)) + ca / (rm[1] + 1e-7f)) / 3.0f;
            cost = fmaxf(cost, 0.0f);
            int lbl = gt_labels[rowb];
            float s = pd_scores[(size_t)gi * NCC + lbl];
            float o2 = ov * ov, o3 = o2 * ov, ov6 = o3 * o3;
            finaln[gi] = nstar;
            fnalign[gi] = (s * ov6) * cost;
            fnov[gi] = ov;
        }
    }
}

// ---- K3: claimed-list pass: per-row pos_align / pos_ov maxes from final assignments ----
__global__ __launch_bounds__(256) void k_post(
    const int* __restrict__ cl_count, const int* __restrict__ clist,
    const int* __restrict__ finaln, const float* __restrict__ fnalign,
    const float* __restrict__ fnov,
    unsigned int* __restrict__ pos_align, unsigned int* __restrict__ pos_ov)
{
    int count = *cl_count;
    int i = blockIdx.x * 256 + threadIdx.x;
    if (i >= count) return;
    int gi = clist[i];
    int b = gi / NAA;
    int nf = finaln[gi];
    int r = (b << 6) + nf;
    atomicMax(&pos_align[r], __float_as_uint(fnalign[gi]));   // all values >= 0
    atomicMax(&pos_ov[r], __float_as_uint(fnov[gi]));
}

// ---- K4: write all outputs (labels, bboxes, full score rows incl. zeros, fg_mask) ----
__global__ __launch_bounds__(256) void k_out(
    const int* __restrict__ gt_labels, const float* __restrict__ gt_bboxes,
    const int* __restrict__ finaln, const float* __restrict__ fnalign,
    const unsigned int* __restrict__ pos_align, const unsigned int* __restrict__ pos_ov,
    float* __restrict__ out)
{
    int i = blockIdx.x * 256 + threadIdx.x;   // b*NAA + a
    if (i >= BSZ * NAA) return;
    int b = i / NAA;
    int nf = finaln[i];
    int tgt = (nf >= 0) ? nf : 0;             // argmax of all-zero column = 0
    int lbl = gt_labels[(b << 6) + tgt];
    float4 g = ((const float4*)gt_bboxes)[(b << 6) + tgt];

    out[i] = (float)lbl;                                          // target_labels
    ((float4*)(out + (size_t)BSZ * NAA))[i] = g;                  // target_bboxes

    float* srow = out + (size_t)BSZ * NAA * 5 + (size_t)i * NCC;  // target_scores row
    float4 z; z.x = 0.0f; z.y = 0.0f; z.z = 0.0f; z.w = 0.0f;
    #pragma unroll
    for (int c4 = 0; c4 < NCC / 4; c4++) ((float4*)srow)[c4] = z;

    float* ofg = out + (size_t)BSZ * NAA * (5 + NCC);             // fg_mask
    if (nf >= 0) {
        float pa = __uint_as_float(pos_align[(b << 6) + nf]);
        float po = __uint_as_float(pos_ov[(b << 6) + nf]);
        srow[lbl] = (fnalign[i] * po) / (pa + 1e-9f);
        ofg[i] = 1.0f;
    } else {
        ofg[i] = 0.0f;
    }
}

extern "C" void kernel_launch(void* const* d_in, const int* in_sizes, int n_in,
                              void* d_out, int out_size, void* d_ws, size_t ws_size,
                              hipStream_t stream)
{
    const float* pd_scores = (const float*)d_in[0];
    const float* pd_bboxes = (const float*)d_in[1];
    const float* anc       = (const float*)d_in[2];
    const int*   gt_labels = (const int*)d_in[3];
    const float* gt_bboxes = (const float*)d_in[4];
    const float* mask_gt   = (const float*)d_in[5];
    float* out = (float*)d_out;

    char* ws = (char*)d_ws;
    const size_t NBA = (size_t)BSZ * NAA * 4;                 // 537600 B per per-anchor array
    size_t off = 0;
    float4*       precomp = (float4*)(ws + off); off += (size_t)BSZ * NAA * 16;   // 2150400
    float4*       rowpre  = (float4*)(ws + off); off += BSZ * NMAXG * 16;         // 16384
    unsigned int* fg      = (unsigned int*)(ws + off); off += NBA;
    int*          finaln  = (int*)(ws + off);          off += NBA;
    float*        fnalign = (float*)(ws + off);        off += NBA;
    float*        fnov    = (float*)(ws + off);        off += NBA;
    unsigned int* posal   = (unsigned int*)(ws + off); off += 4096;
    unsigned int* posov   = (unsigned int*)(ws + off); off += 4096;
    float*        rowmax  = (float*)(ws + off);        off += 12288;
    int*          mc_count= (int*)(ws + off);
    int*          cl_count= (int*)(ws + off + 4);      off += 256;
    int*          mlist   = (int*)(ws + off);          off += MCMAX * 4;
    int*          clist   = (int*)(ws + off);          off += CLMAX * 4;

    // per-call re-init (harness does not re-poison between replays)
    hipMemsetAsync(fg, 0, NBA, stream);
    hipMemsetAsync(finaln, 0xFF, NBA, stream);                // -1
    hipMemsetAsync(posal, 0, 8192, stream);                   // posal + posov
    hipMemsetAsync(mc_count, 0, 8, stream);                   // both counters

    int grid = (BSZ * NAA + 255) / 256;
    k_pre<<<grid, 256, 0, stream>>>(pd_bboxes, gt_bboxes, precomp, rowpre);
    k_rows<<<BSZ * NMAXG, 256, 0, stream>>>(pd_scores, pd_bboxes, anc, gt_labels,
                                            gt_bboxes, mask_gt, precomp, rowpre,
                                            fg, rowmax, finaln, fnalign, fnov,
                                            mc_count, mlist, cl_count, clist);
    k_multi<<<256, 256, 0, stream>>>(pd_scores, pd_bboxes, gt_labels, gt_bboxes,
                                     precomp, rowpre, rowmax, mc_count, mlist,
                                     finaln, fnalign, fnov);
    k_post<<<CLMAX / 256, 256, 0, stream>>>(cl_count, clist, finaln, fnalign, fnov,
                                            posal, posov);
    k_out<<<grid, 256, 0, stream>>>(gt_labels, gt_bboxes, finaln, fnalign, posal, posov, out);
}

// Round 4
// 91.614 us; speedup vs baseline: 2.3943x; 2.3943x over previous
//
#include <hip/hip_runtime.h>
#include <hip/hip_bf16.h>
#include <math.h>

#pragma clang fp contract(off)

#define BSZ   16
#define NMAXG 64
#define NAA   8400
#define NCC   80
#define KTOP  13
#define CAP   768
#define MCMAX 6656
#define CLMAX 13312

// CIoU (clipped at 0) with precomputed ga = w1*h1, pa = w2*h2, da = atan(w2/h2)-atan(w1/h1)
__device__ __forceinline__ float ciou_pre(float gx1, float gy1, float gx2, float gy2,
                                          float px1, float py1, float px2, float py2,
                                          float ga, float pa, float da) {
    const float E = 1e-7f;
    float iw = fminf(gx2, px2) - fmaxf(gx1, px1); iw = fmaxf(iw, 0.0f);
    float ih = fminf(gy2, py2) - fmaxf(gy1, py1); ih = fmaxf(ih, 0.0f);
    float inter = iw * ih;
    float uni = ga + pa - inter + E;
    float iou = inter / uni;
    float cw = fmaxf(gx2, px2) - fminf(gx1, px1);
    float ch = fmaxf(gy2, py2) - fminf(gy1, py1);
    float c2 = cw * cw + ch * ch + E;
    float dx = px1 + px2 - gx1 - gx2;
    float dy = py1 + py2 - gy1 - gy2;
    float rho2 = (dx * dx + dy * dy) / 4.0f;
    float v = 0.4052847345693511f * (da * da);   // 4/pi^2
    float alpha = v / (v - iou + (1.0f + E));
    float r = iou - (rho2 / c2 + v * alpha);
    return fmaxf(r, 0.0f);
}

// ---- K0: per-anchor precompute {pd_r, area, r2, atan(r2)}; per-row {gt_r, area, r1, atan(r1)} ----
__global__ __launch_bounds__(256) void k_pre(
    const float* __restrict__ pd_bboxes, const float* __restrict__ gt_bboxes,
    float4* __restrict__ precomp, float4* __restrict__ rowpre)
{
    int i = blockIdx.x * 256 + threadIdx.x;
    if (i < BSZ * NAA) {
        float4 p = ((const float4*)pd_bboxes)[i];
        float w2 = p.z - p.x, h2 = p.w - p.y + 1e-7f;
        float r2 = w2 / h2;
        float4 q;
        q.x = fminf(w2, h2) / fmaxf(w2, h2);   // pd_r
        q.y = w2 * h2;                         // pa
        q.z = r2;                              // r2
        q.w = atanf(r2);                       // at2
        precomp[i] = q;
    }
    if (i < BSZ * NMAXG) {
        float4 g = ((const float4*)gt_bboxes)[i];
        float w1 = g.z - g.x, h1 = g.w - g.y + 1e-7f;
        float r1 = w1 / h1;
        float4 q;
        q.x = fminf(w1, h1) / fmaxf(w1, h1);   // gt_r
        q.y = w1 * h1;                         // ga
        q.z = r1;                              // r1
        q.w = atanf(r1);                       // at1
        rowpre[i] = q;
    }
}

// ---- K1: one block per (b,n): cost maxes + compaction, metric, LDS top-13, batched claims ----
__global__ __launch_bounds__(256) void k_rows(
    const float* __restrict__ pd_scores, const float* __restrict__ pd_bboxes,
    const float* __restrict__ anc, const int* __restrict__ gt_labels,
    const float* __restrict__ gt_bboxes, const float* __restrict__ mask_gt,
    const float4* __restrict__ precomp, const float4* __restrict__ rowpre,
    unsigned int* __restrict__ fg, float* __restrict__ rowmax,
    int* __restrict__ finaln, float* __restrict__ fnalign, float* __restrict__ fnov,
    int* __restrict__ mc_count, int* __restrict__ mlist,
    int* __restrict__ cl_count, int* __restrict__ clist)
{
    __shared__ int cidx[CAP];
    __shared__ unsigned long long keys[CAP];
    __shared__ float ovs[CAP];
    __shared__ float red[3][4];
    __shared__ int win_a[16];
    __shared__ float win_al[16], win_ov[16];
    __shared__ int s_cnt, s_pos, s_nwin;

    int row = blockIdx.x;            // b*NMAXG + n
    int b = row >> 6, n = row & 63;
    int t = threadIdx.x;
    int wave = t >> 6, lane = t & 63;
    if (t == 0) { s_cnt = 0; s_pos = 0; s_nwin = 0; }
    __syncthreads();

    float4 g  = ((const float4*)gt_bboxes)[row];
    float4 rp = rowpre[row];                      // gt_r, ga, r1, at1
    const float4* pc = precomp + (size_t)b * NAA;
    const float2* ap2 = (const float2*)anc;

    // phase A: full-row maxes of the 3 cost components + compact in-gt anchor list
    float ms = -1e30f, ma = -1e30f, mw = -1e30f;
    for (int a = t; a < NAA; a += 256) {
        float4 q = pc[a];                         // pd_r, pa, r2, at2
        float cs = 1.0f - fabsf(rp.x - q.x) / fmaxf(rp.x, q.x);
        float ca = 1.0f - fabsf(rp.y - q.y) / fmaxf(rp.y, q.y);
        float cw = fminf(rp.z, q.z) / fmaxf(rp.z, q.z);
        ms = fmaxf(ms, cs); ma = fmaxf(ma, ca); mw = fmaxf(mw, cw);
        float2 apv = ap2[a];
        float d = fminf(fminf(apv.x - g.x, apv.y - g.y), fminf(g.z - apv.x, g.w - apv.y));
        if (d > 1e-9f) {
            int p = atomicAdd(&s_cnt, 1);
            if (p < CAP) cidx[p] = a;
        }
    }
    for (int o = 32; o; o >>= 1) {
        ms = fmaxf(ms, __shfl_xor(ms, o));
        ma = fmaxf(ma, __shfl_xor(ma, o));
        mw = fmaxf(mw, __shfl_xor(mw, o));
    }
    if (lane == 0) { red[0][wave] = ms; red[1][wave] = ma; red[2][wave] = mw; }
    __syncthreads();
    ms = fmaxf(fmaxf(red[0][0], red[0][1]), fmaxf(red[0][2], red[0][3]));
    ma = fmaxf(fmaxf(red[1][0], red[1][1]), fmaxf(red[1][2], red[1][3]));
    mw = fmaxf(fmaxf(red[2][0], red[2][1]), fmaxf(red[2][2], red[2][3]));
    if (t == 0) { rowmax[row * 3 + 0] = ms; rowmax[row * 3 + 1] = ma; rowmax[row * 3 + 2] = mw; }
    float dms = ms + 1e-7f, dma = ma + 1e-7f, dmw = mw + 1e-7f;
    int cnt = s_cnt; cnt = cnt < CAP ? cnt : CAP;

    if (mask_gt[row] <= 0.0f) return;   // block-uniform: masked row selects nothing

    // phase B: full align metric at compact anchors only
    int lbl = gt_labels[row];
    const float* sc = pd_scores + (size_t)b * NAA * NCC + lbl;
    const float4* pb = (const float4*)pd_bboxes + (size_t)b * NAA;
    for (int j = t; j < cnt; j += 256) {
        int a = cidx[j];
        float4 p = pb[a];
        float4 q = pc[a];
        float cs = 1.0f - fabsf(rp.x - q.x) / fmaxf(rp.x, q.x);
        float ca = 1.0f - fabsf(rp.y - q.y) / fmaxf(rp.y, q.y);
        float cw = fminf(rp.z, q.z) / fmaxf(rp.z, q.z);
        float cost = ((cs / dms + cw / dmw) + ca / dma) / 3.0f;
        cost = fmaxf(cost, 0.0f);
        float ov = ciou_pre(g.x, g.y, g.z, g.w, p.x, p.y, p.z, p.w,
                            rp.y, q.y, q.w - rp.w);
        float s = sc[(size_t)a * NCC];
        float o2 = ov * ov; float o3 = o2 * ov; float ov6 = o3 * o3;
        float align = (s * ov6) * cost;
        keys[j] = ((unsigned long long)__float_as_uint(align) << 32)
                | (unsigned long long)(0xFFFFFFFFu - (unsigned)a);
        ovs[j] = ov;
        unsigned long long bal = __ballot(align > 0.0f);
        if (lane == 0 && bal) atomicAdd(&s_pos, __popcll(bal));
    }
    __syncthreads();
    if (wave != 0) return;              // wave 0 finishes alone: no barriers below

    int mpos = s_pos;
    int bA = b * NAA;
    int nwin;

    if (mpos >= KTOP) {
        // 13 argmax rounds over LDS keys (value desc, index asc = lax.top_k tie-break).
        // No global ops inside the loop — winners buffered in LDS.
        for (int k = 0; k < KTOP; k++) {
            unsigned long long best = 0ull;
            for (int j = lane; j < cnt; j += 64) {
                unsigned long long kk = keys[j];
                best = kk > best ? kk : best;
            }
            for (int o = 32; o; o >>= 1) {
                unsigned long long ot = __shfl_xor(best, o);
                best = ot > best ? ot : best;
            }
            for (int j = lane; j < cnt; j += 64) {
                if (keys[j] == best) {          // exactly one j (index embedded in key)
                    keys[j] = 0ull;
                    win_a[k]  = (int)(0xFFFFFFFFu - (unsigned)(best & 0xFFFFFFFFull));
                    win_al[k] = __uint_as_float((unsigned)(best >> 32));
                    win_ov[k] = ovs[j];
                }
            }
        }
        nwin = KTOP;
    } else {
        // <13 positives: all positives selected; remaining Z slots go to lowest-index
        // zero-valued anchors of the whole row (only in-gt ones survive the later mask).
        // Total selections <= 13.
        int Z = KTOP - mpos;
        for (int j = lane; j < cnt; j += 64) {
            unsigned long long kk = keys[j];
            int a = (int)(0xFFFFFFFFu - (unsigned)(kk & 0xFFFFFFFFull));
            bool sel;
            if ((kk >> 32) != 0ull) {
                sel = true;
            } else {
                int pcb = 0;
                for (int j2 = 0; j2 < cnt; j2++) {
                    unsigned long long k2 = keys[j2];
                    if ((k2 >> 32) != 0ull) {
                        int a2 = (int)(0xFFFFFFFFu - (unsigned)(k2 & 0xFFFFFFFFull));
                        if (a2 < a) pcb++;
                    }
                }
                sel = (a - pcb) < Z;
            }
            if (sel) {
                int p = atomicAdd(&s_nwin, 1);
                win_a[p]  = a;
                win_al[p] = __uint_as_float((unsigned)(kk >> 32));
                win_ov[p] = ovs[j];
            }
        }
        nwin = s_nwin;
    }

    // parallel claim: lanes 0..nwin-1 issue scattered fg atomics concurrently,
    // then ONE cl_count / mc_count atomic per block with ballot compaction.
    bool isclaim = false, ismulti = false;
    int gi = 0;
    if (lane < nwin) {
        gi = bA + win_a[lane];
        unsigned old = atomicAdd(&fg[gi], 1u);
        if (old == 0u) {
            finaln[gi] = n; fnalign[gi] = win_al[lane]; fnov[gi] = win_ov[lane];
            isclaim = true;
        } else if (old == 1u) {
            ismulti = true;
        }
    }
    unsigned long long cb = __ballot(isclaim);
    unsigned long long mb = __ballot(ismulti);
    int cbase = 0, mbase = 0;
    if (lane == 0) {
        if (cb) cbase = atomicAdd(cl_count, __popcll(cb));
        if (mb) mbase = atomicAdd(mc_count, __popcll(mb));
    }
    cbase = __shfl(cbase, 0);
    mbase = __shfl(mbase, 0);
    unsigned long long below = (lane == 0) ? 0ull : (~0ull >> (64 - lane));
    if (isclaim) clist[cbase + __popcll(cb & below)] = gi;
    if (ismulti) mlist[mbase + __popcll(mb & below)] = gi;
}

// ---- K2: one wave per multi-claimed anchor; 64 gts across 64 lanes ----
__global__ __launch_bounds__(256) void k_multi(
    const float* __restrict__ pd_scores, const float* __restrict__ pd_bboxes,
    const int* __restrict__ gt_labels, const float* __restrict__ gt_bboxes,
    const float4* __restrict__ precomp, const float4* __restrict__ rowpre,
    const float* __restrict__ rowmax, const int* __restrict__ mc_count,
    const int* __restrict__ mlist,
    int* __restrict__ finaln, float* __restrict__ fnalign, float* __restrict__ fnov)
{
    int wave = threadIdx.x >> 6, lane = threadIdx.x & 63;
    int nwaves = gridDim.x << 2;
    int count = *mc_count;
    for (int w = (blockIdx.x << 2) + wave; w < count; w += nwaves) {
        int gi = mlist[w];                          // b*NAA + a
        int b = gi / NAA;
        int rowb = (b << 6) + lane;                 // lane = gt index n
        const float4 p  = ((const float4*)pd_bboxes)[gi];
        const float4 q  = precomp[gi];              // pd_r, pa, r2, at2
        const float4 g  = ((const float4*)gt_bboxes)[rowb];
        const float4 rp = rowpre[rowb];             // gt_r, ga, r1, at1
        float ov = ciou_pre(g.x, g.y, g.z, g.w, p.x, p.y, p.z, p.w,
                            rp.y, q.y, q.w - rp.w);
        // argmax over n, first max wins: value desc, index asc
        unsigned long long key = ((unsigned long long)__float_as_uint(ov) << 32)
                               | (unsigned long long)(63 - lane);
        unsigned long long best = key;
        for (int o = 32; o; o >>= 1) {
            unsigned long long ot = __shfl_xor(best, o);
            best = ot > best ? ot : best;
        }
        int nstar = 63 - (int)(best & 63ull);
        if (lane == nstar) {
            float cs = 1.0f - fabsf(rp.x - q.x) / fmaxf(rp.x, q.x);
            float ca = 1.0f - fabsf(rp.y - q.y) / fmaxf(rp.y, q.y);
            float cw = fminf(rp.z, q.z) / fmaxf(rp.z, q.z);
            const float* rm = rowmax + rowb * 3;
            float cost = ((cs / (rm[0] + 1e-7f) + cw / (rm[2] + 1e-7f)) + ca / (rm[1] + 1e-7f)) / 3.0f;
            cost = fmaxf(cost, 0.0f);
            int lbl = gt_labels[rowb];
            float s = pd_scores[(size_t)gi * NCC + lbl];
            float o2 = ov * ov, o3 = o2 * ov, ov6 = o3 * o3;
            finaln[gi] = nstar;
            fnalign[gi] = (s * ov6) * cost;
            fnov[gi] = ov;
        }
    }
}

// ---- K3: claimed-list pass: per-row pos_align / pos_ov maxes from final assignments ----
__global__ __launch_bounds__(256) void k_post(
    const int* __restrict__ cl_count, const int* __restrict__ clist,
    const int* __restrict__ finaln, const float* __restrict__ fnalign,
    const float* __restrict__ fnov,
    unsigned int* __restrict__ pos_align, unsigned int* __restrict__ pos_ov)
{
    int count = *cl_count;
    int i = blockIdx.x * 256 + threadIdx.x;
    if (i >= count) return;
    int gi = clist[i];
    int b = gi / NAA;
    int nf = finaln[gi];
    int r = (b << 6) + nf;
    atomicMax(&pos_align[r], __float_as_uint(fnalign[gi]));   // all values >= 0
    atomicMax(&pos_ov[r], __float_as_uint(fnov[gi]));
}

// ---- K4: write all outputs (labels, bboxes, full score rows incl. zeros, fg_mask) ----
__global__ __launch_bounds__(256) void k_out(
    const int* __restrict__ gt_labels, const float* __restrict__ gt_bboxes,
    const int* __restrict__ finaln, const float* __restrict__ fnalign,
    const unsigned int* __restrict__ pos_align, const unsigned int* __restrict__ pos_ov,
    float* __restrict__ out)
{
    int i = blockIdx.x * 256 + threadIdx.x;   // b*NAA + a
    if (i >= BSZ * NAA) return;
    int b = i / NAA;
    int nf = finaln[i];
    int tgt = (nf >= 0) ? nf : 0;             // argmax of all-zero column = 0
    int lbl = gt_labels[(b << 6) + tgt];
    float4 g = ((const float4*)gt_bboxes)[(b << 6) + tgt];

    out[i] = (float)lbl;                                          // target_labels
    ((float4*)(out + (size_t)BSZ * NAA))[i] = g;                  // target_bboxes

    float* srow = out + (size_t)BSZ * NAA * 5 + (size_t)i * NCC;  // target_scores row
    float4 z; z.x = 0.0f; z.y = 0.0f; z.z = 0.0f; z.w = 0.0f;
    #pragma unroll
    for (int c4 = 0; c4 < NCC / 4; c4++) ((float4*)srow)[c4] = z;

    float* ofg = out + (size_t)BSZ * NAA * (5 + NCC);             // fg_mask
    if (nf >= 0) {
        float pa = __uint_as_float(pos_align[(b << 6) + nf]);
        float po = __uint_as_float(pos_ov[(b << 6) + nf]);
        srow[lbl] = (fnalign[i] * po) / (pa + 1e-9f);
        ofg[i] = 1.0f;
    } else {
        ofg[i] = 0.0f;
    }
}

extern "C" void kernel_launch(void* const* d_in, const int* in_sizes, int n_in,
                              void* d_out, int out_size, void* d_ws, size_t ws_size,
                              hipStream_t stream)
{
    const float* pd_scores = (const float*)d_in[0];
    const float* pd_bboxes = (const float*)d_in[1];
    const float* anc       = (const float*)d_in[2];
    const int*   gt_labels = (const int*)d_in[3];
    const float* gt_bboxes = (const float*)d_in[4];
    const float* mask_gt   = (const float*)d_in[5];
    float* out = (float*)d_out;

    char* ws = (char*)d_ws;
    const size_t NBA = (size_t)BSZ * NAA * 4;                 // 537600 B per per-anchor array
    size_t off = 0;
    float4*       precomp = (float4*)(ws + off); off += (size_t)BSZ * NAA * 16;   // 2150400
    float4*       rowpre  = (float4*)(ws + off); off += BSZ * NMAXG * 16;         // 16384
    unsigned int* fg      = (unsigned int*)(ws + off); off += NBA;
    int*          finaln  = (int*)(ws + off);          off += NBA;
    float*        fnalign = (float*)(ws + off);        off += NBA;
    float*        fnov    = (float*)(ws + off);        off += NBA;
    unsigned int* posal   = (unsigned int*)(ws + off); off += 4096;
    unsigned int* posov   = (unsigned int*)(ws + off); off += 4096;
    float*        rowmax  = (float*)(ws + off);        off += 12288;
    int*          mc_count= (int*)(ws + off);
    int*          cl_count= (int*)(ws + off + 4);      off += 256;
    int*          mlist   = (int*)(ws + off);          off += MCMAX * 4;
    int*          clist   = (int*)(ws + off);          off += CLMAX * 4;

    // per-call re-init (harness does not re-poison between replays)
    hipMemsetAsync(fg, 0, NBA, stream);
    hipMemsetAsync(finaln, 0xFF, NBA, stream);                // -1
    hipMemsetAsync(posal, 0, 8192, stream);                   // posal + posov
    hipMemsetAsync(mc_count, 0, 8, stream);                   // both counters

    int grid = (BSZ * NAA + 255) / 256;
    k_pre<<<grid, 256, 0, stream>>>(pd_bboxes, gt_bboxes, precomp, rowpre);
    k_rows<<<BSZ * NMAXG, 256, 0, stream>>>(pd_scores, pd_bboxes, anc, gt_labels,
                                            gt_bboxes, mask_gt, precomp, rowpre,
                                            fg, rowmax, finaln, fnalign, fnov,
                                            mc_count, mlist, cl_count, clist);
    k_multi<<<256, 256, 0, stream>>>(pd_scores, pd_bboxes, gt_labels, gt_bboxes,
                                     precomp, rowpre, rowmax, mc_count, mlist,
                                     finaln, fnalign, fnov);
    k_post<<<CLMAX / 256, 256, 0, stream>>>(cl_count, clist, finaln, fnalign, fnov,
                                            posal, posov);
    k_out<<<grid, 256, 0, stream>>>(gt_labels, gt_bboxes, finaln, fnalign, posal, posov, out);
}